// Round 2
// 94.057 us; speedup vs baseline: 1.0071x; 1.0071x over previous
//
#include <hip/hip_runtime.h>

// CubicalLayer gather: out[i] = X[idx[i].x * 4096 + idx[i].y]
// H = W = 4096, N_IDX = 524288. Output is flat 524288 fp32 (reshape(-1,2)
// is a no-op on flat layout).
//
// Profile evidence (R0): timed region = 2x 42.2us 256MiB workspace-poison
// fills (harness) + ~10us gather. Gather data floor ~48 MiB (~7.6us):
// 4 MiB idx + 2 MiB out + ~42 MiB unique 128B lines of X (Poisson; the
// 256 MiB fill flushes L3 each iteration so X re-fetches from HBM).
// This version: 2 points/thread -> 16B/lane idx load, two independent
// gathers in flight (ILP), packed 8B store, nontemporal hints on the
// streaming (read-once/write-once) idx and out traffic.
//
// R1 lesson: __builtin_nontemporal_* requires NATIVE vector types
// (ext_vector_type), not HIP_vector_type structs like int4/float2.

#define N_IDX 524288

typedef int   vint4   __attribute__((ext_vector_type(4)));
typedef float vfloat2 __attribute__((ext_vector_type(2)));

__global__ __launch_bounds__(256) void cubical_gather_kernel(
    const float* __restrict__ X,
    const vint4* __restrict__ idx2,   // two (row,col) points per 16B
    vfloat2* __restrict__ out2,
    int n2)                           // = n/2 point-pairs
{
    int i = blockIdx.x * blockDim.x + threadIdx.x;
    if (i < n2) {
        // 16B/lane coalesced, nontemporal (read-once stream; keep L2 for X)
        vint4 p = __builtin_nontemporal_load(&idx2[i]);
        // rows/cols in [0,4096): offsets fit 32-bit (max 2^24). Two
        // independent random gathers issue back-to-back -> 2x memory-level
        // parallelism per lane on the latency-bound path.
        float a = X[(p.x << 12) + p.y];
        float b = X[(p.z << 12) + p.w];
        vfloat2 o; o.x = a; o.y = b;
        // write-once stream, no reuse
        __builtin_nontemporal_store(o, &out2[i]);
    }
}

extern "C" void kernel_launch(void* const* d_in, const int* in_sizes, int n_in,
                              void* d_out, int out_size, void* d_ws, size_t ws_size,
                              hipStream_t stream) {
    const float* X     = (const float*)d_in[0];
    const vint4* idx2  = (const vint4*)d_in[1];  // (N_IDX, 2) int32 -> 16B pairs
    vfloat2* out2 = (vfloat2*)d_out;

    int n  = in_sizes[1] / 2;                    // 524288 gather points
    int n2 = n / 2;                              // 262144 pairs (N_IDX is even)
    int block = 256;
    int grid = (n2 + block - 1) / block;         // 1024 blocks
    cubical_gather_kernel<<<grid, block, 0, stream>>>(X, idx2, out2, n2);
}